// Round 22
// baseline (391.812 us; speedup 1.0000x reference)
//
#include <hip/hip_runtime.h>
#include <hip/hip_bf16.h>

// T=16, N=4, Cin=hidden=64, C4=256, H=W=64
typedef float        f32x4  __attribute__((ext_vector_type(4)));
typedef unsigned int u32x4  __attribute__((ext_vector_type(4)));
typedef __bf16       bf16x8 __attribute__((ext_vector_type(8)));

__device__ __forceinline__ unsigned short f2bf(float f) {
    unsigned u = __builtin_bit_cast(unsigned, f);
    u += 0x7fffu + ((u >> 16) & 1u);          // RTN-even (finite inputs)
    return (unsigned short)(u >> 16);
}
__device__ __forceinline__ float bf2f(unsigned short u) {
    union { unsigned ui; float f; } c; c.ui = ((unsigned)u) << 16; return c.f;
}
// async global->LDS, 16B per lane (dest must be uniform base + lane*16)
__device__ __forceinline__ void gload_lds16(const void* g, void* l) {
    __builtin_amdgcn_global_load_lds(
        (const __attribute__((address_space(1))) unsigned int*)g,
        (__attribute__((address_space(3))) unsigned int*)l, 16, 0, 0);
}

// ---------------------------------------------------------------------------
// xT: [img][pix][ci] bf16  <-  x [img][ci][pix] f32 (r15-verified transpose)
// ---------------------------------------------------------------------------
__global__ __launch_bounds__(256) void k_xT(const float* __restrict__ x,
                                            unsigned short* __restrict__ xT) {
    __shared__ unsigned int tl[256 * 32];     // 32 KB
    const int img = blockIdx.x >> 4;
    const int p0  = (blockIdx.x & 15) * 256;
    const int tid = threadIdx.x;
    const float* xi = x + (size_t)img * 64 * 4096 + p0 + tid;
#pragma unroll
    for (int cp = 0; cp < 32; ++cp) {
        float a = xi[(size_t)(2 * cp) * 4096];
        float b = xi[(size_t)(2 * cp + 1) * 4096];
        unsigned v = (unsigned)f2bf(a) | ((unsigned)f2bf(b) << 16);
        tl[tid * 32 + (cp ^ (tid & 31))] = v;
    }
    __syncthreads();
    unsigned short* dst = xT + ((size_t)img * 4096 + p0) * 64;
#pragma unroll
    for (int k = 0; k < 8; ++k) {
        int c = tid + k * 256;
        int pix = c >> 3, slot = c & 7;
        unsigned w[4];
#pragma unroll
        for (int i = 0; i < 4; ++i)
            w[i] = tl[pix * 32 + ((slot * 4 + i) ^ (pix & 31))];
        *(u32x4*)(dst + (size_t)pix * 64 + slot * 8) = *(u32x4*)w;
    }
}

// ---------------------------------------------------------------------------
// Pack BOTH weights (grid 1152).  A bf16 [row][kb][tap][4 slots of 16B]
// (kb-major).  Phase-uniform chunk swizzle (r21-verified): stored slot s
// holds source chunk s ^ ((row>>1)&3).  Rows gate-interleaved (r = hc*4+g).
// ---------------------------------------------------------------------------
__global__ __launch_bounds__(256) void k_pack2(const float* __restrict__ Wx,
                                               const float* __restrict__ Wh,
                                               unsigned short* __restrict__ Axp,
                                               unsigned short* __restrict__ Ahp) {
    int b = blockIdx.x;
    const float* W = (b < 576) ? Wx : Wh;
    unsigned short* Ap = (b < 576) ? Axp : Ahp;
    int idx = (b % 576) * 256 + threadIdx.x;
    if (idx >= 256 * 576) return;
    int row = idx / 576, k = idx % 576;
    int kb = k / 288, r2 = k % 288;
    int tap = r2 / 32, w32 = r2 % 32;
    int s = w32 >> 3, e = w32 & 7;
    int ci = kb * 32 + ((s ^ ((row >> 1) & 3)) << 3) + e;  // phase-uniform swz
    int co = (row & 3) * 64 + (row >> 2);
    Ap[idx] = f2bf(W[((size_t)co * 64 + ci) * 9 + tap]);
}

// ---------------------------------------------------------------------------
// x2h conv (r21 geometry + T4 counted-vmcnt): 512-thread blocks, 128 couts
// share ONE halo; A TRIPLE-buffered via global_load_lds; per-iteration
// s_waitcnt vmcnt(1) + raw s_barrier (prefetch stays in flight across the
// barrier -- never drained to 0 in the main loop).  LDS 66048 B -> 2/CU.
// grid 2048 = 64img*16tile*2cog2; XCD decode co-locates a tile's 2 blocks.
// ---------------------------------------------------------------------------
__global__ __launch_bounds__(512) void k_conv0(
    const unsigned short* __restrict__ src,   // xT [img][4096][64] bf16
    const unsigned short* __restrict__ Ap,    // packed Wx (kb-major)
    unsigned short* __restrict__ ybf,         // y out [img][pix][256r]
    float2* __restrict__ prt)                 // [256r][1024] BN partials
{
    constexpr int HR = 18;

    __shared__ __align__(16) unsigned short halo[HR * 18 * 64]; // 41472 B
    __shared__ __align__(16) unsigned short As[3][4096];        // 24576 B

    const int bid  = blockIdx.x;
    const int xcd  = bid & 7;
    const int sidx = bid >> 3;
    const int grp2 = sidx & 1;
    const int pairG = (sidx >> 1) * 8 + xcd;  // 0..1023
    const int tile = pairG & 15;
    const int img  = pairG >> 4;
    const int py0 = (tile >> 2) * 16, px0 = (tile & 3) * 16;
    const int tid = threadIdx.x;
    const int wv = tid >> 6;                  // 0..7
    const int rgrp = wv >> 2, wq = wv & 3;
    const int lane = tid & 63;
    const int cl = lane & 15, q = lane >> 4;
    const int rowbase = grp2 * 128;

    f32x4 acc[4][4];
#pragma unroll
    for (int m = 0; m < 4; ++m)
#pragma unroll
        for (int n = 0; n < 4; ++n)
            acc[m][n] = (f32x4){0.f, 0.f, 0.f, 0.f};

    {
        const char* agp = (const char*)Ap +
            (size_t)(rowbase + (tid >> 2)) * 1152 + (tid & 3) * 16;
        gload_lds16(agp,      (char*)&As[0][0] + tid * 16);    // ks' = 0
        gload_lds16(agp + 64, (char*)&As[1][0] + tid * 16);    // ks' = 1

        const unsigned short* sb = src + (size_t)img * 4096 * 64;
        char* hB = (char*)halo;
        for (int tau = tid; tau < HR * 144; tau += 512) {
            int s = tau & 7, hcc = (tau >> 3) % 18, hrr = tau / 144;
            int gy = py0 + hrr - 1, gx = px0 + hcc - 1;
            u32x4 v = {0u, 0u, 0u, 0u};
            if ((unsigned)gy < 64u && (unsigned)gx < 64u)
                v = *(const u32x4*)(sb + ((gy * 64 + gx) * 64 + s * 8));
            *(u32x4*)(hB + (hrr * 18 + hcc) * 128 + ((s * 16) ^ ((hcc & 7) << 4))) = v;
        }
        __syncthreads();                       // prologue: full drain (once)

        int aoff[4];
#pragma unroll
        for (int m = 0; m < 4; ++m)
            aoff[m] = (rgrp * 64 + m * 16 + cl) * 64 +
                      ((q * 16) ^ ((((cl >> 1) & 3)) << 4));   // phase-uniform

        const char* AsRd = (const char*)&As[0][0];
#pragma unroll
        for (int ks = 0; ks < 18; ++ks) {                  // ks' = kb*9+tap
            const int buf = ks % 3;
            if (ks < 16)                       // prefetch ks+2 -> (ks+2)%3
                gload_lds16(agp + (ks + 2) * 64,
                            (char*)&As[(ks + 2) % 3][0] + tid * 16);

            const int kb = ks / 9, tap = ks % 9;
            const int ky = tap / 3, kx = tap - ky * 3;

            u32x4 af[4];
#pragma unroll
            for (int m = 0; m < 4; ++m)
                af[m] = *(const u32x4*)(AsRd + buf * 8192 + aoff[m]);

            int hcv  = cl + kx;
            int cbase = hcv * 128 + ((kb * 64 + q * 16) ^ ((hcv & 7) << 4));
#pragma unroll
            for (int n = 0; n < 4; ++n) {
                int hr = wq * 4 + n + ky;
                u32x4 bv = *(const u32x4*)(hB + hr * 2304 + cbase);
                bf16x8 bfr = __builtin_bit_cast(bf16x8, bv);
#pragma unroll
                for (int m = 0; m < 4; ++m)
                    acc[m][n] = __builtin_amdgcn_mfma_f32_16x16x32_bf16(
                        __builtin_bit_cast(bf16x8, af[m]), bfr, acc[m][n], 0, 0, 0);
            }
            // T4: counted vmcnt -- keep the newest prefetch in flight
            if (ks < 16) asm volatile("s_waitcnt vmcnt(1)" ::: "memory");
            else         asm volatile("s_waitcnt vmcnt(0)" ::: "memory");
            __builtin_amdgcn_s_barrier();
            asm volatile("" ::: "memory");
        }
    }

    // ---- y[img][pix][r]: 8B packed store per (m,n) ----
#pragma unroll
    for (int m = 0; m < 4; ++m) {
        int co = rowbase + rgrp * 64 + m * 16 + q * 4;
#pragma unroll
        for (int n = 0; n < 4; ++n) {
            int pix = (py0 + wq * 4 + n) * 64 + px0 + cl;
            uint2 w;
            w.x = (unsigned)f2bf(acc[m][n][0]) | ((unsigned)f2bf(acc[m][n][1]) << 16);
            w.y = (unsigned)f2bf(acc[m][n][2]) | ((unsigned)f2bf(acc[m][n][3]) << 16);
            *(uint2*)(ybf + ((size_t)img * 4096 + pix) * 256 + co) = w;
        }
    }
    // ---- fused BN partial stats: per-block 128-channel (sum, sumsq) ----
    float* bnred = (float*)halo;         // 4 KB reuse (k-loop reads done)
#pragma unroll
    for (int m = 0; m < 4; ++m) {
#pragma unroll
        for (int j = 0; j < 4; ++j) {
            float s = 0.f, qq = 0.f;
#pragma unroll
            for (int n = 0; n < 4; ++n) {
                float v = acc[m][n][j];
                s += v; qq += v * v;
            }
#pragma unroll
            for (int mask = 1; mask <= 8; mask <<= 1) {
                s  += __shfl_xor(s,  mask, 64);
                qq += __shfl_xor(qq, mask, 64);
            }
            if (cl == 0) {
                int ci_ = ((rgrp * 4 + wq) * 4 + q) * 16 + m * 4 + j;  // 0..511
                bnred[ci_ * 2]     = s;
                bnred[ci_ * 2 + 1] = qq;
            }
        }
    }
    __syncthreads();
    if (tid < 128) {
        int rg = tid >> 6, m_ = (tid >> 4) & 3, qj = tid & 15;
        float s = 0.f, qq = 0.f;
#pragma unroll
        for (int w = 0; w < 4; ++w) {
            int idx = (((rg * 4 + w) * 4 + (qj >> 2)) * 16 + m_ * 4 + (qj & 3)) * 2;
            s += bnred[idx]; qq += bnred[idx + 1];
        }
        prt[(size_t)(rowbase + tid) * 1024 + img * 16 + tile] = make_float2(s, qq);
    }
}

// ---------------------------------------------------------------------------
// BN finalize (r16-verified).
// ---------------------------------------------------------------------------
__global__ __launch_bounds__(256) void k_bn_fin(
    const float2* __restrict__ prt, const float* __restrict__ bx,
    const float* __restrict__ gamma, const float* __restrict__ beta,
    float* __restrict__ ss) {
    int c = blockIdx.x;
    const float2* p = prt + (size_t)c * 1024;
    float s = 0.f, sq = 0.f;
    for (int i = threadIdx.x; i < 1024; i += 256) {
        float2 v = p[i]; s += v.x; sq += v.y;
    }
    __shared__ float rs[256], rq[256];
    int tid = threadIdx.x;
    rs[tid] = s; rq[tid] = sq;
    __syncthreads();
    for (int off = 128; off > 0; off >>= 1) {
        if (tid < off) { rs[tid] += rs[tid + off]; rq[tid] += rq[tid + off]; }
        __syncthreads();
    }
    if (tid == 0) {
        int co = (c & 3) * 64 + (c >> 2);
        float mean = rs[0] * (1.f / 262144.f);
        float var  = rq[0] * (1.f / 262144.f) - mean * mean;
        float sc   = gamma[co] * rsqrtf(var + 1e-5f);
        ss[c]       = sc;
        ss[256 + c] = beta[co] - mean * sc;   // bx cancels in train-mode BN
        (void)bx;
    }
}

// ---------------------------------------------------------------------------
// LSTM step (r21 geometry + T4 counted-vmcnt): TH=8, N_=2, grid 512, full
// 8-slot halo, kb-major decode, phase-uniform A swizzle, A triple-buffer,
// y+c register prefetch, t=0 gates c to 0.  LDS 35328 B.
// ---------------------------------------------------------------------------
__global__ __launch_bounds__(256) void k_step(
    const unsigned short* __restrict__ hin,
    const unsigned short* __restrict__ Ap,
    const unsigned short* __restrict__ ybf,
    const float* __restrict__ ss,
    float* __restrict__ cst,
    unsigned short* __restrict__ hout,
    float* __restrict__ out,
    int t, int first)
{
    constexpr int TH = 8, N_ = 2, HR = 10;

    __shared__ __align__(16) unsigned short halo[HR * 18 * 64]; // 23040 B
    __shared__ __align__(16) unsigned short As[3][2048];        // 12288 B

    const int bid  = blockIdx.x;
    const int xcd  = bid & 7;
    const int sidx = bid >> 3;
    const int grp  = sidx & 3;
    const int pairG = (sidx >> 2) * 8 + xcd;  // 0..127
    const int tile = pairG & 31;
    const int img  = pairG >> 5;
    const int py0 = (tile >> 2) * TH, px0 = (tile & 3) * 16;
    const int tid = threadIdx.x;
    const int wv = tid >> 6, lane = tid & 63;
    const int cl = lane & 15, q = lane >> 4;
    const int rowbase = grp * 64;

    // ---- y + c prefetch (HBM latency hidden under k-loop) ----
    uint2 ypre[4][N_];
    float cpre[4][N_];
#pragma unroll
    for (int m = 0; m < 4; ++m) {
        int hc = grp * 16 + m * 4 + q;
#pragma unroll
        for (int n = 0; n < N_; ++n) {
            int pix = (py0 + wv * N_ + n) * 64 + px0 + cl;
            ypre[m][n] = *(const uint2*)(ybf +
                ((size_t)(t * 4 + img) * 4096 + pix) * 256 + hc * 4);
            cpre[m][n] = first ? 0.f : cst[((size_t)img * 64 + hc) * 4096 + pix];
        }
    }

    f32x4 acc[4][N_];
#pragma unroll
    for (int m = 0; m < 4; ++m)
#pragma unroll
        for (int n = 0; n < N_; ++n)
            acc[m][n] = (f32x4){0.f, 0.f, 0.f, 0.f};

    if (!first) {
        const char* agp = (const char*)Ap +
            (size_t)(rowbase + (tid >> 2)) * 1152 + (tid & 3) * 16;
        gload_lds16(agp,      (char*)&As[0][0] + tid * 16);    // ks' = 0
        gload_lds16(agp + 64, (char*)&As[1][0] + tid * 16);    // ks' = 1

        const unsigned short* sb = hin + (size_t)img * 4096 * 64;
        char* hB = (char*)halo;
        for (int tau = tid; tau < HR * 144; tau += 256) {
            int s = tau & 7, hcc = (tau >> 3) % 18, hrr = tau / 144;
            int gy = py0 + hrr - 1, gx = px0 + hcc - 1;
            u32x4 v = {0u, 0u, 0u, 0u};
            if ((unsigned)gy < 64u && (unsigned)gx < 64u)
                v = *(const u32x4*)(sb + ((gy * 64 + gx) * 64 + s * 8));
            *(u32x4*)(hB + (hrr * 18 + hcc) * 128 + ((s * 16) ^ ((hcc & 7) << 4))) = v;
        }
        __syncthreads();                       // prologue: full drain (once)

        int aoff[4];
#pragma unroll
        for (int m = 0; m < 4; ++m)
            aoff[m] = (m * 16 + cl) * 64 +
                      ((q * 16) ^ ((((cl >> 1) & 3)) << 4));   // phase-uniform

        const char* AsRd = (const char*)&As[0][0];
#pragma unroll
        for (int ks = 0; ks < 18; ++ks) {
            const int buf = ks % 3;
            if (ks < 16)
                gload_lds16(agp + (ks + 2) * 64,
                            (char*)&As[(ks + 2) % 3][0] + tid * 16);

            const int kb = ks / 9, tap = ks % 9;
            const int ky = tap / 3, kx = tap - ky * 3;

            u32x4 af[4];
#pragma unroll
            for (int m = 0; m < 4; ++m)
                af[m] = *(const u32x4*)(AsRd + buf * 4096 + aoff[m]);

            int hcv  = cl + kx;
            int cbase = hcv * 128 + ((kb * 64 + q * 16) ^ ((hcv & 7) << 4));
#pragma unroll
            for (int n = 0; n < N_; ++n) {
                int hr = wv * N_ + n + ky;
                u32x4 bv = *(const u32x4*)(hB + hr * 2304 + cbase);
                bf16x8 bfr = __builtin_bit_cast(bf16x8, bv);
#pragma unroll
                for (int m = 0; m < 4; ++m)
                    acc[m][n] = __builtin_amdgcn_mfma_f32_16x16x32_bf16(
                        __builtin_bit_cast(bf16x8, af[m]), bfr, acc[m][n], 0, 0, 0);
            }
            if (ks < 16) asm volatile("s_waitcnt vmcnt(1)" ::: "memory");
            else         asm volatile("s_waitcnt vmcnt(0)" ::: "memory");
            __builtin_amdgcn_s_barrier();
            asm volatile("" ::: "memory");
        }
    }

    // ---- epilogue: gates, c, h ----
    unsigned short* hbounce = halo;
    const f32x4* sc4 = (const f32x4*)ss;
    const f32x4* sh4 = (const f32x4*)(ss + 256);
#pragma unroll
    for (int m = 0; m < 4; ++m) {
        int hc = grp * 16 + m * 4 + q;
        f32x4 sc = sc4[hc], sh = sh4[hc];
#pragma unroll
        for (int n = 0; n < N_; ++n) {
            int pix = (py0 + wv * N_ + n) * 64 + px0 + cl;
            uint2 yv = ypre[m][n];
            float tmp[4];
            tmp[0] = acc[m][n][0] + sc[0] * bf2f((unsigned short)(yv.x & 0xffffu)) + sh[0];
            tmp[1] = acc[m][n][1] + sc[1] * bf2f((unsigned short)(yv.x >> 16))     + sh[1];
            tmp[2] = acc[m][n][2] + sc[2] * bf2f((unsigned short)(yv.y & 0xffffu)) + sh[2];
            tmp[3] = acc[m][n][3] + sc[3] * bf2f((unsigned short)(yv.y >> 16))     + sh[3];
            float iv = 1.f / (1.f + __expf(-tmp[0]));
            float fv = 1.f / (1.f + __expf(-tmp[1]));
            float ov = 1.f / (1.f + __expf(-tmp[2]));
            float e2 = __expf(2.f * tmp[3]);
            float gv = 1.f - 2.f / (e2 + 1.f);
            size_t cidx = ((size_t)img * 64 + hc) * 4096 + pix;
            float cnew = fv * cpre[m][n] + iv * gv;
            cst[cidx] = cnew;
            float e2c = __expf(2.f * cnew);
            float hv  = ov * (1.f - 2.f / (e2c + 1.f));
            out[((size_t)(t * 4 + img) * 64 + hc) * 4096 + pix] = hv;
            hbounce[((wv * N_ + n) * 16 + cl) * 16 + m * 4 + q] = f2bf(hv);
        }
    }
    __syncthreads();
    if (tid < TH * 16) {
        int pixg = (py0 + (tid >> 4)) * 64 + px0 + (tid & 15);
        u32x4* dst = (u32x4*)(hout + ((size_t)img * 4096 + pixg) * 64 + grp * 16);
        u32x4* s0  = (u32x4*)(hbounce + tid * 16);
        dst[0] = s0[0];
        dst[1] = s0[1];
    }
}

// ---------------------------------------------------------------------------
extern "C" void kernel_launch(void* const* d_in, const int* in_sizes, int n_in,
                              void* d_out, int out_size, void* d_ws, size_t ws_size,
                              hipStream_t stream) {
    const float* x     = (const float*)d_in[0];
    const float* Wx    = (const float*)d_in[1];
    const float* bx    = (const float*)d_in[2];
    const float* gamma = (const float*)d_in[3];
    const float* beta  = (const float*)d_in[4];
    const float* Wh    = (const float*)d_in[5];
    float* out = (float*)d_out;

    char* ws = (char*)d_ws;
    unsigned short* y   = (unsigned short*)ws;                  // 134,217,728
    unsigned short* Axp = (unsigned short*)(ws + 134217728);    //     294,912
    unsigned short* Ahp = (unsigned short*)(ws + 134512640);    //     294,912
    float*          ss  = (float*)(ws + 134807552);             //       2,048
    float*          cs  = (float*)(ws + 134809600);             //   4,194,304
    // prt and hA share a 2 MB slot: prt is produced by k_conv0 and fully
    // consumed by k_bn_fin before k_step first writes hA (at t=1).
    float2*         prt = (float2*)(ws + 139003904);            //   2,097,152
    unsigned short* hA  = (unsigned short*)(ws + 139003904);    //   (alias)
    unsigned short* hB  = (unsigned short*)(ws + 141101056);    //   2,097,152
    // total 143,198,208 B

    // xT scratch lives in d_out (dead once steps start overwriting it)
    unsigned short* xT = (unsigned short*)d_out;

    k_xT   <<<1024, 256, 0, stream>>>(x, xT);
    k_pack2<<<1152, 256, 0, stream>>>(Wx, Wh, Axp, Ahp);

    k_conv0<<<2048, 512, 0, stream>>>(xT, Axp, y, prt);
    k_bn_fin<<<256, 256, 0, stream>>>(prt, bx, gamma, beta, ss);

    unsigned short* hbuf[2] = {hA, hB};
    for (int t = 0; t < 16; ++t) {
        k_step<<<512, 256, 0, stream>>>(hbuf[t & 1], Ahp, y, ss, cs,
                                        hbuf[(t + 1) & 1], out, t, t == 0 ? 1 : 0);
    }
}

// Round 23
// 373.331 us; speedup vs baseline: 1.0495x; 1.0495x over previous
//
#include <hip/hip_runtime.h>
#include <hip/hip_bf16.h>

// T=16, N=4, Cin=hidden=64, C4=256, H=W=64
typedef float        f32x4  __attribute__((ext_vector_type(4)));
typedef unsigned int u32x4  __attribute__((ext_vector_type(4)));
typedef __bf16       bf16x8 __attribute__((ext_vector_type(8)));

__device__ __forceinline__ unsigned short f2bf(float f) {
    unsigned u = __builtin_bit_cast(unsigned, f);
    u += 0x7fffu + ((u >> 16) & 1u);          // RTN-even (finite inputs)
    return (unsigned short)(u >> 16);
}
__device__ __forceinline__ float bf2f(unsigned short u) {
    union { unsigned ui; float f; } c; c.ui = ((unsigned)u) << 16; return c.f;
}
// async global->LDS, 16B per lane (dest must be uniform base + lane*16)
__device__ __forceinline__ void gload_lds16(const void* g, void* l) {
    __builtin_amdgcn_global_load_lds(
        (const __attribute__((address_space(1))) unsigned int*)g,
        (__attribute__((address_space(3))) unsigned int*)l, 16, 0, 0);
}

// ---------------------------------------------------------------------------
// xT: [img][pix][ci] bf16  <-  x [img][ci][pix] f32 (r15-verified transpose)
// ---------------------------------------------------------------------------
__global__ __launch_bounds__(256) void k_xT(const float* __restrict__ x,
                                            unsigned short* __restrict__ xT) {
    __shared__ unsigned int tl[256 * 32];     // 32 KB
    const int img = blockIdx.x >> 4;
    const int p0  = (blockIdx.x & 15) * 256;
    const int tid = threadIdx.x;
    const float* xi = x + (size_t)img * 64 * 4096 + p0 + tid;
#pragma unroll
    for (int cp = 0; cp < 32; ++cp) {
        float a = xi[(size_t)(2 * cp) * 4096];
        float b = xi[(size_t)(2 * cp + 1) * 4096];
        unsigned v = (unsigned)f2bf(a) | ((unsigned)f2bf(b) << 16);
        tl[tid * 32 + (cp ^ (tid & 31))] = v;
    }
    __syncthreads();
    unsigned short* dst = xT + ((size_t)img * 4096 + p0) * 64;
#pragma unroll
    for (int k = 0; k < 8; ++k) {
        int c = tid + k * 256;
        int pix = c >> 3, slot = c & 7;
        unsigned w[4];
#pragma unroll
        for (int i = 0; i < 4; ++i)
            w[i] = tl[pix * 32 + ((slot * 4 + i) ^ (pix & 31))];
        *(u32x4*)(dst + (size_t)pix * 64 + slot * 8) = *(u32x4*)w;
    }
}

// ---------------------------------------------------------------------------
// Pack BOTH weights (grid 1152).  A bf16 [row][kb][tap][4 slots of 16B]
// (kb-major: ks' = kb*9+tap, slab offset = ks'*64).  PHASE-UNIFORM chunk
// swizzle (r21-verified): stored slot s holds source chunk s ^ ((row>>1)&3).
// Rows gate-interleaved (r = hc*4+g <-> co = g*64+hc).
// ---------------------------------------------------------------------------
__global__ __launch_bounds__(256) void k_pack2(const float* __restrict__ Wx,
                                               const float* __restrict__ Wh,
                                               unsigned short* __restrict__ Axp,
                                               unsigned short* __restrict__ Ahp) {
    int b = blockIdx.x;
    const float* W = (b < 576) ? Wx : Wh;
    unsigned short* Ap = (b < 576) ? Axp : Ahp;
    int idx = (b % 576) * 256 + threadIdx.x;
    if (idx >= 256 * 576) return;
    int row = idx / 576, k = idx % 576;
    int kb = k / 288, r2 = k % 288;
    int tap = r2 / 32, w32 = r2 % 32;
    int s = w32 >> 3, e = w32 & 7;
    int ci = kb * 32 + ((s ^ ((row >> 1) & 3)) << 3) + e;  // phase-uniform swz
    int co = (row & 3) * 64 + (row >> 2);
    Ap[idx] = f2bf(W[((size_t)co * 64 + ci) * 9 + tap]);
}

// ---------------------------------------------------------------------------
// x2h conv (r21-verified optimum): 512-thread blocks, 128 couts share ONE
// halo, LDS 57.9 KB -> 2 blocks/CU = 16 waves.  kb-major unrolled 18-ks loop.
// grid 2048 = 64img*16tile*2cog2; XCD decode co-locates a tile's 2 blocks.
// ---------------------------------------------------------------------------
__global__ __launch_bounds__(512) void k_conv0(
    const unsigned short* __restrict__ src,   // xT [img][4096][64] bf16
    const unsigned short* __restrict__ Ap,    // packed Wx (kb-major)
    unsigned short* __restrict__ ybf,         // y out [img][pix][256r]
    float2* __restrict__ prt)                 // [256r][1024] BN partials
{
    constexpr int HR = 18;

    __shared__ __align__(16) unsigned short halo[HR * 18 * 64]; // 41472 B
    __shared__ __align__(16) unsigned short As[2][128 * 32];    // 16384 B

    const int bid  = blockIdx.x;
    const int xcd  = bid & 7;
    const int sidx = bid >> 3;
    const int grp2 = sidx & 1;                // 2 cout groups of 128
    const int pairG = (sidx >> 1) * 8 + xcd;  // 0..1023
    const int tile = pairG & 15;
    const int img  = pairG >> 4;
    const int py0 = (tile >> 2) * 16, px0 = (tile & 3) * 16;
    const int tid = threadIdx.x;
    const int wv = tid >> 6;                  // 0..7
    const int rgrp = wv >> 2, wq = wv & 3;    // cout-half / pixel-quad
    const int lane = tid & 63;
    const int cl = lane & 15, q = lane >> 4;
    const int rowbase = grp2 * 128;

    f32x4 acc[4][4];
#pragma unroll
    for (int m = 0; m < 4; ++m)
#pragma unroll
        for (int n = 0; n < 4; ++n)
            acc[m][n] = (f32x4){0.f, 0.f, 0.f, 0.f};

    {
        // A staging: 128 rows x 64B per ks; 512 thr x 16B = one slab/issue
        const char* agp = (const char*)Ap +
            (size_t)(rowbase + (tid >> 2)) * 1152 + (tid & 3) * 16;
        gload_lds16(agp, (char*)&As[0][0] + tid * 16);     // ks' = 0

        const unsigned short* sb = src + (size_t)img * 4096 * 64;
        char* hB = (char*)halo;
        for (int tau = tid; tau < HR * 144; tau += 512) {
            int s = tau & 7, hcc = (tau >> 3) % 18, hrr = tau / 144;
            int gy = py0 + hrr - 1, gx = px0 + hcc - 1;
            u32x4 v = {0u, 0u, 0u, 0u};
            if ((unsigned)gy < 64u && (unsigned)gx < 64u)
                v = *(const u32x4*)(sb + ((gy * 64 + gx) * 64 + s * 8));
            *(u32x4*)(hB + (hrr * 18 + hcc) * 128 + ((s * 16) ^ ((hcc & 7) << 4))) = v;
        }
        __syncthreads();

        int aoff[4];
#pragma unroll
        for (int m = 0; m < 4; ++m)
            aoff[m] = (rgrp * 64 + m * 16 + cl) * 64 +
                      ((q * 16) ^ ((((cl >> 1) & 3)) << 4));   // phase-uniform

        const char* AsRd = (const char*)&As[0][0];
#pragma unroll
        for (int ks = 0; ks < 18; ++ks) {                  // ks' = kb*9+tap
            const int buf = ks & 1;
            if (ks < 17)
                gload_lds16(agp + (ks + 1) * 64, (char*)&As[buf ^ 1][0] + tid * 16);

            const int kb = ks / 9, tap = ks % 9;
            const int ky = tap / 3, kx = tap - ky * 3;

            u32x4 af[4];
#pragma unroll
            for (int m = 0; m < 4; ++m)
                af[m] = *(const u32x4*)(AsRd + buf * 8192 + aoff[m]);

            int hcv  = cl + kx;
            int cbase = hcv * 128 + ((kb * 64 + q * 16) ^ ((hcv & 7) << 4));
#pragma unroll
            for (int n = 0; n < 4; ++n) {
                int hr = wq * 4 + n + ky;
                u32x4 bv = *(const u32x4*)(hB + hr * 2304 + cbase);
                bf16x8 bfr = __builtin_bit_cast(bf16x8, bv);
#pragma unroll
                for (int m = 0; m < 4; ++m)
                    acc[m][n] = __builtin_amdgcn_mfma_f32_16x16x32_bf16(
                        __builtin_bit_cast(bf16x8, af[m]), bfr, acc[m][n], 0, 0, 0);
            }
            __syncthreads();                               // drains prefetch
        }
    }

    // ---- y[img][pix][r]: 8B packed store per (m,n) ----
#pragma unroll
    for (int m = 0; m < 4; ++m) {
        int co = rowbase + rgrp * 64 + m * 16 + q * 4;
#pragma unroll
        for (int n = 0; n < 4; ++n) {
            int pix = (py0 + wq * 4 + n) * 64 + px0 + cl;
            uint2 w;
            w.x = (unsigned)f2bf(acc[m][n][0]) | ((unsigned)f2bf(acc[m][n][1]) << 16);
            w.y = (unsigned)f2bf(acc[m][n][2]) | ((unsigned)f2bf(acc[m][n][3]) << 16);
            *(uint2*)(ybf + ((size_t)img * 4096 + pix) * 256 + co) = w;
        }
    }
    // ---- fused BN partial stats: per-block 128-channel (sum, sumsq) ----
    float* bnred = (float*)halo;         // 4 KB reuse
#pragma unroll
    for (int m = 0; m < 4; ++m) {
#pragma unroll
        for (int j = 0; j < 4; ++j) {
            float s = 0.f, qq = 0.f;
#pragma unroll
            for (int n = 0; n < 4; ++n) {
                float v = acc[m][n][j];
                s += v; qq += v * v;
            }
#pragma unroll
            for (int mask = 1; mask <= 8; mask <<= 1) {
                s  += __shfl_xor(s,  mask, 64);
                qq += __shfl_xor(qq, mask, 64);
            }
            if (cl == 0) {
                int ci_ = ((rgrp * 4 + wq) * 4 + q) * 16 + m * 4 + j;  // 0..511
                bnred[ci_ * 2]     = s;
                bnred[ci_ * 2 + 1] = qq;
            }
        }
    }
    __syncthreads();
    if (tid < 128) {
        int rg = tid >> 6, m_ = (tid >> 4) & 3, qj = tid & 15;
        float s = 0.f, qq = 0.f;
#pragma unroll
        for (int w = 0; w < 4; ++w) {
            int idx = (((rg * 4 + w) * 4 + (qj >> 2)) * 16 + m_ * 4 + (qj & 3)) * 2;
            s += bnred[idx]; qq += bnred[idx + 1];
        }
        prt[(size_t)(rowbase + tid) * 1024 + img * 16 + tile] = make_float2(s, qq);
    }
}

// ---------------------------------------------------------------------------
// BN finalize (r16-verified).
// ---------------------------------------------------------------------------
__global__ __launch_bounds__(256) void k_bn_fin(
    const float2* __restrict__ prt, const float* __restrict__ bx,
    const float* __restrict__ gamma, const float* __restrict__ beta,
    float* __restrict__ ss) {
    int c = blockIdx.x;
    const float2* p = prt + (size_t)c * 1024;
    float s = 0.f, sq = 0.f;
    for (int i = threadIdx.x; i < 1024; i += 256) {
        float2 v = p[i]; s += v.x; sq += v.y;
    }
    __shared__ float rs[256], rq[256];
    int tid = threadIdx.x;
    rs[tid] = s; rq[tid] = sq;
    __syncthreads();
    for (int off = 128; off > 0; off >>= 1) {
        if (tid < off) { rs[tid] += rs[tid + off]; rq[tid] += rq[tid + off]; }
        __syncthreads();
    }
    if (tid == 0) {
        int co = (c & 3) * 64 + (c >> 2);
        float mean = rs[0] * (1.f / 262144.f);
        float var  = rq[0] * (1.f / 262144.f) - mean * mean;
        float sc   = gamma[co] * rsqrtf(var + 1e-5f);
        ss[c]       = sc;
        ss[256 + c] = beta[co] - mean * sc;   // bx cancels in train-mode BN
        (void)bx;
    }
}

// ---------------------------------------------------------------------------
// LSTM step (r21-verified): TH=8, N_=2, grid 512, full 8-slot halo,
// kb-major decode, phase-uniform A swizzle, y+c register prefetch,
// t=0 gates c to 0.
// ---------------------------------------------------------------------------
__global__ __launch_bounds__(256) void k_step(
    const unsigned short* __restrict__ hin,
    const unsigned short* __restrict__ Ap,
    const unsigned short* __restrict__ ybf,
    const float* __restrict__ ss,
    float* __restrict__ cst,
    unsigned short* __restrict__ hout,
    float* __restrict__ out,
    int t, int first)
{
    constexpr int TH = 8, N_ = 2, HR = 10;

    __shared__ __align__(16) unsigned short halo[HR * 18 * 64]; // 23040 B
    __shared__ __align__(16) unsigned short As[2][2048];        //  8192 B

    const int bid  = blockIdx.x;
    const int xcd  = bid & 7;
    const int sidx = bid >> 3;
    const int grp  = sidx & 3;
    const int pairG = (sidx >> 2) * 8 + xcd;  // 0..127
    const int tile = pairG & 31;
    const int img  = pairG >> 5;
    const int py0 = (tile >> 2) * TH, px0 = (tile & 3) * 16;
    const int tid = threadIdx.x;
    const int wv = tid >> 6, lane = tid & 63;
    const int cl = lane & 15, q = lane >> 4;
    const int rowbase = grp * 64;

    // ---- y + c prefetch (HBM latency hidden under k-loop) ----
    uint2 ypre[4][N_];
    float cpre[4][N_];
#pragma unroll
    for (int m = 0; m < 4; ++m) {
        int hc = grp * 16 + m * 4 + q;
#pragma unroll
        for (int n = 0; n < N_; ++n) {
            int pix = (py0 + wv * N_ + n) * 64 + px0 + cl;
            ypre[m][n] = *(const uint2*)(ybf +
                ((size_t)(t * 4 + img) * 4096 + pix) * 256 + hc * 4);
            cpre[m][n] = first ? 0.f : cst[((size_t)img * 64 + hc) * 4096 + pix];
        }
    }

    f32x4 acc[4][N_];
#pragma unroll
    for (int m = 0; m < 4; ++m)
#pragma unroll
        for (int n = 0; n < N_; ++n)
            acc[m][n] = (f32x4){0.f, 0.f, 0.f, 0.f};

    if (!first) {
        const char* agp = (const char*)Ap +
            (size_t)(rowbase + (tid >> 2)) * 1152 + (tid & 3) * 16;
        gload_lds16(agp, (char*)&As[0][0] + tid * 16);

        const unsigned short* sb = hin + (size_t)img * 4096 * 64;
        char* hB = (char*)halo;
        for (int tau = tid; tau < HR * 144; tau += 256) {
            int s = tau & 7, hcc = (tau >> 3) % 18, hrr = tau / 144;
            int gy = py0 + hrr - 1, gx = px0 + hcc - 1;
            u32x4 v = {0u, 0u, 0u, 0u};
            if ((unsigned)gy < 64u && (unsigned)gx < 64u)
                v = *(const u32x4*)(sb + ((gy * 64 + gx) * 64 + s * 8));
            *(u32x4*)(hB + (hrr * 18 + hcc) * 128 + ((s * 16) ^ ((hcc & 7) << 4))) = v;
        }
        __syncthreads();

        int aoff[4];
#pragma unroll
        for (int m = 0; m < 4; ++m)
            aoff[m] = (m * 16 + cl) * 64 +
                      ((q * 16) ^ ((((cl >> 1) & 3)) << 4));   // phase-uniform

        const char* AsRd = (const char*)&As[0][0];
#pragma unroll
        for (int ks = 0; ks < 18; ++ks) {
            const int buf = ks & 1;
            if (ks < 17)
                gload_lds16(agp + (ks + 1) * 64, (char*)&As[buf ^ 1][0] + tid * 16);

            const int kb = ks / 9, tap = ks % 9;
            const int ky = tap / 3, kx = tap - ky * 3;

            u32x4 af[4];
#pragma unroll
            for (int m = 0; m < 4; ++m)
                af[m] = *(const u32x4*)(AsRd + buf * 4096 + aoff[m]);

            int hcv  = cl + kx;
            int cbase = hcv * 128 + ((kb * 64 + q * 16) ^ ((hcv & 7) << 4));
#pragma unroll
            for (int n = 0; n < N_; ++n) {
                int hr = wv * N_ + n + ky;
                u32x4 bv = *(const u32x4*)(hB + hr * 2304 + cbase);
                bf16x8 bfr = __builtin_bit_cast(bf16x8, bv);
#pragma unroll
                for (int m = 0; m < 4; ++m)
                    acc[m][n] = __builtin_amdgcn_mfma_f32_16x16x32_bf16(
                        __builtin_bit_cast(bf16x8, af[m]), bfr, acc[m][n], 0, 0, 0);
            }
            __syncthreads();
        }
    }

    // ---- epilogue: gates, c, h ----
    unsigned short* hbounce = halo;
    const f32x4* sc4 = (const f32x4*)ss;
    const f32x4* sh4 = (const f32x4*)(ss + 256);
#pragma unroll
    for (int m = 0; m < 4; ++m) {
        int hc = grp * 16 + m * 4 + q;
        f32x4 sc = sc4[hc], sh = sh4[hc];
#pragma unroll
        for (int n = 0; n < N_; ++n) {
            int pix = (py0 + wv * N_ + n) * 64 + px0 + cl;
            uint2 yv = ypre[m][n];
            float tmp[4];
            tmp[0] = acc[m][n][0] + sc[0] * bf2f((unsigned short)(yv.x & 0xffffu)) + sh[0];
            tmp[1] = acc[m][n][1] + sc[1] * bf2f((unsigned short)(yv.x >> 16))     + sh[1];
            tmp[2] = acc[m][n][2] + sc[2] * bf2f((unsigned short)(yv.y & 0xffffu)) + sh[2];
            tmp[3] = acc[m][n][3] + sc[3] * bf2f((unsigned short)(yv.y >> 16))     + sh[3];
            float iv = 1.f / (1.f + __expf(-tmp[0]));
            float fv = 1.f / (1.f + __expf(-tmp[1]));
            float ov = 1.f / (1.f + __expf(-tmp[2]));
            float e2 = __expf(2.f * tmp[3]);
            float gv = 1.f - 2.f / (e2 + 1.f);
            size_t cidx = ((size_t)img * 64 + hc) * 4096 + pix;
            float cnew = fv * cpre[m][n] + iv * gv;
            cst[cidx] = cnew;
            float e2c = __expf(2.f * cnew);
            float hv  = ov * (1.f - 2.f / (e2c + 1.f));
            out[((size_t)(t * 4 + img) * 64 + hc) * 4096 + pix] = hv;
            hbounce[((wv * N_ + n) * 16 + cl) * 16 + m * 4 + q] = f2bf(hv);
        }
    }
    __syncthreads();
    if (tid < TH * 16) {
        int pixg = (py0 + (tid >> 4)) * 64 + px0 + (tid & 15);
        u32x4* dst = (u32x4*)(hout + ((size_t)img * 4096 + pixg) * 64 + grp * 16);
        u32x4* s0  = (u32x4*)(hbounce + tid * 16);
        dst[0] = s0[0];
        dst[1] = s0[1];
    }
}

// ---------------------------------------------------------------------------
extern "C" void kernel_launch(void* const* d_in, const int* in_sizes, int n_in,
                              void* d_out, int out_size, void* d_ws, size_t ws_size,
                              hipStream_t stream) {
    const float* x     = (const float*)d_in[0];
    const float* Wx    = (const float*)d_in[1];
    const float* bx    = (const float*)d_in[2];
    const float* gamma = (const float*)d_in[3];
    const float* beta  = (const float*)d_in[4];
    const float* Wh    = (const float*)d_in[5];
    float* out = (float*)d_out;

    char* ws = (char*)d_ws;
    unsigned short* y   = (unsigned short*)ws;                  // 134,217,728
    unsigned short* Axp = (unsigned short*)(ws + 134217728);    //     294,912
    unsigned short* Ahp = (unsigned short*)(ws + 134512640);    //     294,912
    float*          ss  = (float*)(ws + 134807552);             //       2,048
    float*          cs  = (float*)(ws + 134809600);             //   4,194,304
    // prt and hA share a 2 MB slot: prt is produced by k_conv0 and fully
    // consumed by k_bn_fin before k_step first writes hA (at t=1).
    float2*         prt = (float2*)(ws + 139003904);            //   2,097,152
    unsigned short* hA  = (unsigned short*)(ws + 139003904);    //   (alias)
    unsigned short* hB  = (unsigned short*)(ws + 141101056);    //   2,097,152
    // total 143,198,208 B

    // xT scratch lives in d_out (dead once steps start overwriting it)
    unsigned short* xT = (unsigned short*)d_out;

    k_xT   <<<1024, 256, 0, stream>>>(x, xT);
    k_pack2<<<1152, 256, 0, stream>>>(Wx, Wh, Axp, Ahp);

    k_conv0<<<2048, 512, 0, stream>>>(xT, Axp, y, prt);
    k_bn_fin<<<256, 256, 0, stream>>>(prt, bx, gamma, beta, ss);

    unsigned short* hbuf[2] = {hA, hB};
    for (int t = 0; t < 16; ++t) {
        k_step<<<512, 256, 0, stream>>>(hbuf[t & 1], Ahp, y, ss, cs,
                                        hbuf[(t + 1) & 1], out, t, t == 0 ? 1 : 0);
    }
}

// Round 24
// 369.880 us; speedup vs baseline: 1.0593x; 1.0093x over previous
//
#include <hip/hip_runtime.h>
#include <hip/hip_bf16.h>

// T=16, N=4, Cin=hidden=64, C4=256, H=W=64
typedef float        f32x4  __attribute__((ext_vector_type(4)));
typedef unsigned int u32x4  __attribute__((ext_vector_type(4)));
typedef __bf16       bf16x8 __attribute__((ext_vector_type(8)));

__device__ __forceinline__ unsigned short f2bf(float f) {
    unsigned u = __builtin_bit_cast(unsigned, f);
    u += 0x7fffu + ((u >> 16) & 1u);          // RTN-even (finite inputs)
    return (unsigned short)(u >> 16);
}
__device__ __forceinline__ float bf2f(unsigned short u) {
    union { unsigned ui; float f; } c; c.ui = ((unsigned)u) << 16; return c.f;
}
// async global->LDS, 16B per lane (dest must be uniform base + lane*16)
__device__ __forceinline__ void gload_lds16(const void* g, void* l) {
    __builtin_amdgcn_global_load_lds(
        (const __attribute__((address_space(1))) unsigned int*)g,
        (__attribute__((address_space(3))) unsigned int*)l, 16, 0, 0);
}

// ---------------------------------------------------------------------------
// xT: [img][pix][ci] bf16  <-  x [img][ci][pix] f32 (r15-verified transpose)
// ---------------------------------------------------------------------------
__global__ __launch_bounds__(256) void k_xT(const float* __restrict__ x,
                                            unsigned short* __restrict__ xT) {
    __shared__ unsigned int tl[256 * 32];     // 32 KB
    const int img = blockIdx.x >> 4;
    const int p0  = (blockIdx.x & 15) * 256;
    const int tid = threadIdx.x;
    const float* xi = x + (size_t)img * 64 * 4096 + p0 + tid;
#pragma unroll
    for (int cp = 0; cp < 32; ++cp) {
        float a = xi[(size_t)(2 * cp) * 4096];
        float b = xi[(size_t)(2 * cp + 1) * 4096];
        unsigned v = (unsigned)f2bf(a) | ((unsigned)f2bf(b) << 16);
        tl[tid * 32 + (cp ^ (tid & 31))] = v;
    }
    __syncthreads();
    unsigned short* dst = xT + ((size_t)img * 4096 + p0) * 64;
#pragma unroll
    for (int k = 0; k < 8; ++k) {
        int c = tid + k * 256;
        int pix = c >> 3, slot = c & 7;
        unsigned w[4];
#pragma unroll
        for (int i = 0; i < 4; ++i)
            w[i] = tl[pix * 32 + ((slot * 4 + i) ^ (pix & 31))];
        *(u32x4*)(dst + (size_t)pix * 64 + slot * 8) = *(u32x4*)w;
    }
}

// ---------------------------------------------------------------------------
// Pack BOTH weights (grid 1152).  A bf16 [row][kb][tap][4 slots of 16B]
// (kb-major: ks' = kb*9+tap, slab offset = ks'*64).  PHASE-UNIFORM chunk
// swizzle (r21-verified): stored slot s holds source chunk s ^ ((row>>1)&3).
// Rows gate-interleaved (r = hc*4+g <-> co = g*64+hc).
// ---------------------------------------------------------------------------
__global__ __launch_bounds__(256) void k_pack2(const float* __restrict__ Wx,
                                               const float* __restrict__ Wh,
                                               unsigned short* __restrict__ Axp,
                                               unsigned short* __restrict__ Ahp) {
    int b = blockIdx.x;
    const float* W = (b < 576) ? Wx : Wh;
    unsigned short* Ap = (b < 576) ? Axp : Ahp;
    int idx = (b % 576) * 256 + threadIdx.x;
    if (idx >= 256 * 576) return;
    int row = idx / 576, k = idx % 576;
    int kb = k / 288, r2 = k % 288;
    int tap = r2 / 32, w32 = r2 % 32;
    int s = w32 >> 3, e = w32 & 7;
    int ci = kb * 32 + ((s ^ ((row >> 1) & 3)) << 3) + e;  // phase-uniform swz
    int co = (row & 3) * 64 + (row >> 2);
    Ap[idx] = f2bf(W[((size_t)co * 64 + ci) * 9 + tap]);
}

// ---------------------------------------------------------------------------
// x2h conv (r21/r23-verified optimum, UNCHANGED): 512-thread blocks, 128
// couts share ONE halo, LDS 57.9 KB -> 2 blocks/CU = 16 waves.  kb-major
// unrolled 18-ks loop.  grid 2048; XCD decode co-locates a tile's 2 blocks.
// ---------------------------------------------------------------------------
__global__ __launch_bounds__(512) void k_conv0(
    const unsigned short* __restrict__ src,   // xT [img][4096][64] bf16
    const unsigned short* __restrict__ Ap,    // packed Wx (kb-major)
    unsigned short* __restrict__ ybf,         // y out [img][pix][256r]
    float2* __restrict__ prt)                 // [256r][1024] BN partials
{
    constexpr int HR = 18;

    __shared__ __align__(16) unsigned short halo[HR * 18 * 64]; // 41472 B
    __shared__ __align__(16) unsigned short As[2][128 * 32];    // 16384 B

    const int bid  = blockIdx.x;
    const int xcd  = bid & 7;
    const int sidx = bid >> 3;
    const int grp2 = sidx & 1;                // 2 cout groups of 128
    const int pairG = (sidx >> 1) * 8 + xcd;  // 0..1023
    const int tile = pairG & 15;
    const int img  = pairG >> 4;
    const int py0 = (tile >> 2) * 16, px0 = (tile & 3) * 16;
    const int tid = threadIdx.x;
    const int wv = tid >> 6;                  // 0..7
    const int rgrp = wv >> 2, wq = wv & 3;    // cout-half / pixel-quad
    const int lane = tid & 63;
    const int cl = lane & 15, q = lane >> 4;
    const int rowbase = grp2 * 128;

    f32x4 acc[4][4];
#pragma unroll
    for (int m = 0; m < 4; ++m)
#pragma unroll
        for (int n = 0; n < 4; ++n)
            acc[m][n] = (f32x4){0.f, 0.f, 0.f, 0.f};

    {
        // A staging: 128 rows x 64B per ks; 512 thr x 16B = one slab/issue
        const char* agp = (const char*)Ap +
            (size_t)(rowbase + (tid >> 2)) * 1152 + (tid & 3) * 16;
        gload_lds16(agp, (char*)&As[0][0] + tid * 16);     // ks' = 0

        const unsigned short* sb = src + (size_t)img * 4096 * 64;
        char* hB = (char*)halo;
        for (int tau = tid; tau < HR * 144; tau += 512) {
            int s = tau & 7, hcc = (tau >> 3) % 18, hrr = tau / 144;
            int gy = py0 + hrr - 1, gx = px0 + hcc - 1;
            u32x4 v = {0u, 0u, 0u, 0u};
            if ((unsigned)gy < 64u && (unsigned)gx < 64u)
                v = *(const u32x4*)(sb + ((gy * 64 + gx) * 64 + s * 8));
            *(u32x4*)(hB + (hrr * 18 + hcc) * 128 + ((s * 16) ^ ((hcc & 7) << 4))) = v;
        }
        __syncthreads();

        int aoff[4];
#pragma unroll
        for (int m = 0; m < 4; ++m)
            aoff[m] = (rgrp * 64 + m * 16 + cl) * 64 +
                      ((q * 16) ^ ((((cl >> 1) & 3)) << 4));   // phase-uniform

        const char* AsRd = (const char*)&As[0][0];
#pragma unroll
        for (int ks = 0; ks < 18; ++ks) {                  // ks' = kb*9+tap
            const int buf = ks & 1;
            if (ks < 17)
                gload_lds16(agp + (ks + 1) * 64, (char*)&As[buf ^ 1][0] + tid * 16);

            const int kb = ks / 9, tap = ks % 9;
            const int ky = tap / 3, kx = tap - ky * 3;

            u32x4 af[4];
#pragma unroll
            for (int m = 0; m < 4; ++m)
                af[m] = *(const u32x4*)(AsRd + buf * 8192 + aoff[m]);

            int hcv  = cl + kx;
            int cbase = hcv * 128 + ((kb * 64 + q * 16) ^ ((hcv & 7) << 4));
#pragma unroll
            for (int n = 0; n < 4; ++n) {
                int hr = wq * 4 + n + ky;
                u32x4 bv = *(const u32x4*)(hB + hr * 2304 + cbase);
                bf16x8 bfr = __builtin_bit_cast(bf16x8, bv);
#pragma unroll
                for (int m = 0; m < 4; ++m)
                    acc[m][n] = __builtin_amdgcn_mfma_f32_16x16x32_bf16(
                        __builtin_bit_cast(bf16x8, af[m]), bfr, acc[m][n], 0, 0, 0);
            }
            __syncthreads();                               // drains prefetch
        }
    }

    // ---- y[img][pix][r]: 8B packed store per (m,n) ----
#pragma unroll
    for (int m = 0; m < 4; ++m) {
        int co = rowbase + rgrp * 64 + m * 16 + q * 4;
#pragma unroll
        for (int n = 0; n < 4; ++n) {
            int pix = (py0 + wq * 4 + n) * 64 + px0 + cl;
            uint2 w;
            w.x = (unsigned)f2bf(acc[m][n][0]) | ((unsigned)f2bf(acc[m][n][1]) << 16);
            w.y = (unsigned)f2bf(acc[m][n][2]) | ((unsigned)f2bf(acc[m][n][3]) << 16);
            *(uint2*)(ybf + ((size_t)img * 4096 + pix) * 256 + co) = w;
        }
    }
    // ---- fused BN partial stats: per-block 128-channel (sum, sumsq) ----
    float* bnred = (float*)halo;         // 4 KB reuse
#pragma unroll
    for (int m = 0; m < 4; ++m) {
#pragma unroll
        for (int j = 0; j < 4; ++j) {
            float s = 0.f, qq = 0.f;
#pragma unroll
            for (int n = 0; n < 4; ++n) {
                float v = acc[m][n][j];
                s += v; qq += v * v;
            }
#pragma unroll
            for (int mask = 1; mask <= 8; mask <<= 1) {
                s  += __shfl_xor(s,  mask, 64);
                qq += __shfl_xor(qq, mask, 64);
            }
            if (cl == 0) {
                int ci_ = ((rgrp * 4 + wq) * 4 + q) * 16 + m * 4 + j;  // 0..511
                bnred[ci_ * 2]     = s;
                bnred[ci_ * 2 + 1] = qq;
            }
        }
    }
    __syncthreads();
    if (tid < 128) {
        int rg = tid >> 6, m_ = (tid >> 4) & 3, qj = tid & 15;
        float s = 0.f, qq = 0.f;
#pragma unroll
        for (int w = 0; w < 4; ++w) {
            int idx = (((rg * 4 + w) * 4 + (qj >> 2)) * 16 + m_ * 4 + (qj & 3)) * 2;
            s += bnred[idx]; qq += bnred[idx + 1];
        }
        prt[(size_t)(rowbase + tid) * 1024 + img * 16 + tile] = make_float2(s, qq);
    }
}

// ---------------------------------------------------------------------------
// BN finalize (r16-verified).
// ---------------------------------------------------------------------------
__global__ __launch_bounds__(256) void k_bn_fin(
    const float2* __restrict__ prt, const float* __restrict__ bx,
    const float* __restrict__ gamma, const float* __restrict__ beta,
    float* __restrict__ ss) {
    int c = blockIdx.x;
    const float2* p = prt + (size_t)c * 1024;
    float s = 0.f, sq = 0.f;
    for (int i = threadIdx.x; i < 1024; i += 256) {
        float2 v = p[i]; s += v.x; sq += v.y;
    }
    __shared__ float rs[256], rq[256];
    int tid = threadIdx.x;
    rs[tid] = s; rq[tid] = sq;
    __syncthreads();
    for (int off = 128; off > 0; off >>= 1) {
        if (tid < off) { rs[tid] += rs[tid + off]; rq[tid] += rq[tid + off]; }
        __syncthreads();
    }
    if (tid == 0) {
        int co = (c & 3) * 64 + (c >> 2);
        float mean = rs[0] * (1.f / 262144.f);
        float var  = rq[0] * (1.f / 262144.f) - mean * mean;
        float sc   = gamma[co] * rsqrtf(var + 1e-5f);
        ss[c]       = sc;
        ss[256 + c] = beta[co] - mean * sc;   // bx cancels in train-mode BN
        (void)bx;
    }
}

// ---------------------------------------------------------------------------
// LSTM step (r22-verified T4 variant): TH=8, N_=2, grid 512, full 8-slot
// halo, kb-major decode, phase-uniform A swizzle, A TRIPLE-buffer with
// counted vmcnt(1) + raw s_barrier (prefetch in flight across barrier),
// y+c register prefetch, t=0 gates c to 0.  LDS 35328 B (256-thr -> no
// occupancy cliff, unlike conv0's 512-thr geometry).
// ---------------------------------------------------------------------------
__global__ __launch_bounds__(256) void k_step(
    const unsigned short* __restrict__ hin,
    const unsigned short* __restrict__ Ap,
    const unsigned short* __restrict__ ybf,
    const float* __restrict__ ss,
    float* __restrict__ cst,
    unsigned short* __restrict__ hout,
    float* __restrict__ out,
    int t, int first)
{
    constexpr int TH = 8, N_ = 2, HR = 10;

    __shared__ __align__(16) unsigned short halo[HR * 18 * 64]; // 23040 B
    __shared__ __align__(16) unsigned short As[3][2048];        // 12288 B

    const int bid  = blockIdx.x;
    const int xcd  = bid & 7;
    const int sidx = bid >> 3;
    const int grp  = sidx & 3;
    const int pairG = (sidx >> 2) * 8 + xcd;  // 0..127
    const int tile = pairG & 31;
    const int img  = pairG >> 5;
    const int py0 = (tile >> 2) * TH, px0 = (tile & 3) * 16;
    const int tid = threadIdx.x;
    const int wv = tid >> 6, lane = tid & 63;
    const int cl = lane & 15, q = lane >> 4;
    const int rowbase = grp * 64;

    // ---- y + c prefetch (HBM latency hidden under k-loop) ----
    uint2 ypre[4][N_];
    float cpre[4][N_];
#pragma unroll
    for (int m = 0; m < 4; ++m) {
        int hc = grp * 16 + m * 4 + q;
#pragma unroll
        for (int n = 0; n < N_; ++n) {
            int pix = (py0 + wv * N_ + n) * 64 + px0 + cl;
            ypre[m][n] = *(const uint2*)(ybf +
                ((size_t)(t * 4 + img) * 4096 + pix) * 256 + hc * 4);
            cpre[m][n] = first ? 0.f : cst[((size_t)img * 64 + hc) * 4096 + pix];
        }
    }

    f32x4 acc[4][N_];
#pragma unroll
    for (int m = 0; m < 4; ++m)
#pragma unroll
        for (int n = 0; n < N_; ++n)
            acc[m][n] = (f32x4){0.f, 0.f, 0.f, 0.f};

    if (!first) {
        const char* agp = (const char*)Ap +
            (size_t)(rowbase + (tid >> 2)) * 1152 + (tid & 3) * 16;
        gload_lds16(agp,      (char*)&As[0][0] + tid * 16);    // ks' = 0
        gload_lds16(agp + 64, (char*)&As[1][0] + tid * 16);    // ks' = 1

        const unsigned short* sb = hin + (size_t)img * 4096 * 64;
        char* hB = (char*)halo;
        for (int tau = tid; tau < HR * 144; tau += 256) {
            int s = tau & 7, hcc = (tau >> 3) % 18, hrr = tau / 144;
            int gy = py0 + hrr - 1, gx = px0 + hcc - 1;
            u32x4 v = {0u, 0u, 0u, 0u};
            if ((unsigned)gy < 64u && (unsigned)gx < 64u)
                v = *(const u32x4*)(sb + ((gy * 64 + gx) * 64 + s * 8));
            *(u32x4*)(hB + (hrr * 18 + hcc) * 128 + ((s * 16) ^ ((hcc & 7) << 4))) = v;
        }
        __syncthreads();                       // prologue: full drain (once)

        int aoff[4];
#pragma unroll
        for (int m = 0; m < 4; ++m)
            aoff[m] = (m * 16 + cl) * 64 +
                      ((q * 16) ^ ((((cl >> 1) & 3)) << 4));   // phase-uniform

        const char* AsRd = (const char*)&As[0][0];
#pragma unroll
        for (int ks = 0; ks < 18; ++ks) {
            const int buf = ks % 3;
            if (ks < 16)                       // prefetch ks+2 -> (ks+2)%3
                gload_lds16(agp + (ks + 2) * 64,
                            (char*)&As[(ks + 2) % 3][0] + tid * 16);

            const int kb = ks / 9, tap = ks % 9;
            const int ky = tap / 3, kx = tap - ky * 3;

            u32x4 af[4];
#pragma unroll
            for (int m = 0; m < 4; ++m)
                af[m] = *(const u32x4*)(AsRd + buf * 4096 + aoff[m]);

            int hcv  = cl + kx;
            int cbase = hcv * 128 + ((kb * 64 + q * 16) ^ ((hcv & 7) << 4));
#pragma unroll
            for (int n = 0; n < N_; ++n) {
                int hr = wv * N_ + n + ky;
                u32x4 bv = *(const u32x4*)(hB + hr * 2304 + cbase);
                bf16x8 bfr = __builtin_bit_cast(bf16x8, bv);
#pragma unroll
                for (int m = 0; m < 4; ++m)
                    acc[m][n] = __builtin_amdgcn_mfma_f32_16x16x32_bf16(
                        __builtin_bit_cast(bf16x8, af[m]), bfr, acc[m][n], 0, 0, 0);
            }
            // T4: counted vmcnt -- keep the newest prefetch in flight
            if (ks < 16) asm volatile("s_waitcnt vmcnt(1)" ::: "memory");
            else         asm volatile("s_waitcnt vmcnt(0)" ::: "memory");
            __builtin_amdgcn_s_barrier();
            asm volatile("" ::: "memory");
        }
    }

    // ---- epilogue: gates, c, h ----
    unsigned short* hbounce = halo;
    const f32x4* sc4 = (const f32x4*)ss;
    const f32x4* sh4 = (const f32x4*)(ss + 256);
#pragma unroll
    for (int m = 0; m < 4; ++m) {
        int hc = grp * 16 + m * 4 + q;
        f32x4 sc = sc4[hc], sh = sh4[hc];
#pragma unroll
        for (int n = 0; n < N_; ++n) {
            int pix = (py0 + wv * N_ + n) * 64 + px0 + cl;
            uint2 yv = ypre[m][n];
            float tmp[4];
            tmp[0] = acc[m][n][0] + sc[0] * bf2f((unsigned short)(yv.x & 0xffffu)) + sh[0];
            tmp[1] = acc[m][n][1] + sc[1] * bf2f((unsigned short)(yv.x >> 16))     + sh[1];
            tmp[2] = acc[m][n][2] + sc[2] * bf2f((unsigned short)(yv.y & 0xffffu)) + sh[2];
            tmp[3] = acc[m][n][3] + sc[3] * bf2f((unsigned short)(yv.y >> 16))     + sh[3];
            float iv = 1.f / (1.f + __expf(-tmp[0]));
            float fv = 1.f / (1.f + __expf(-tmp[1]));
            float ov = 1.f / (1.f + __expf(-tmp[2]));
            float e2 = __expf(2.f * tmp[3]);
            float gv = 1.f - 2.f / (e2 + 1.f);
            size_t cidx = ((size_t)img * 64 + hc) * 4096 + pix;
            float cnew = fv * cpre[m][n] + iv * gv;
            cst[cidx] = cnew;
            float e2c = __expf(2.f * cnew);
            float hv  = ov * (1.f - 2.f / (e2c + 1.f));
            out[((size_t)(t * 4 + img) * 64 + hc) * 4096 + pix] = hv;
            hbounce[((wv * N_ + n) * 16 + cl) * 16 + m * 4 + q] = f2bf(hv);
        }
    }
    __syncthreads();
    if (tid < TH * 16) {
        int pixg = (py0 + (tid >> 4)) * 64 + px0 + (tid & 15);
        u32x4* dst = (u32x4*)(hout + ((size_t)img * 4096 + pixg) * 64 + grp * 16);
        u32x4* s0  = (u32x4*)(hbounce + tid * 16);
        dst[0] = s0[0];
        dst[1] = s0[1];
    }
}

// ---------------------------------------------------------------------------
extern "C" void kernel_launch(void* const* d_in, const int* in_sizes, int n_in,
                              void* d_out, int out_size, void* d_ws, size_t ws_size,
                              hipStream_t stream) {
    const float* x     = (const float*)d_in[0];
    const float* Wx    = (const float*)d_in[1];
    const float* bx    = (const float*)d_in[2];
    const float* gamma = (const float*)d_in[3];
    const float* beta  = (const float*)d_in[4];
    const float* Wh    = (const float*)d_in[5];
    float* out = (float*)d_out;

    char* ws = (char*)d_ws;
    unsigned short* y   = (unsigned short*)ws;                  // 134,217,728
    unsigned short* Axp = (unsigned short*)(ws + 134217728);    //     294,912
    unsigned short* Ahp = (unsigned short*)(ws + 134512640);    //     294,912
    float*          ss  = (float*)(ws + 134807552);             //       2,048
    float*          cs  = (float*)(ws + 134809600);             //   4,194,304
    // prt and hA share a 2 MB slot: prt is produced by k_conv0 and fully
    // consumed by k_bn_fin before k_step first writes hA (at t=1).
    float2*         prt = (float2*)(ws + 139003904);            //   2,097,152
    unsigned short* hA  = (unsigned short*)(ws + 139003904);    //   (alias)
    unsigned short* hB  = (unsigned short*)(ws + 141101056);    //   2,097,152
    // total 143,198,208 B

    // xT scratch lives in d_out (dead once steps start overwriting it)
    unsigned short* xT = (unsigned short*)d_out;

    k_xT   <<<1024, 256, 0, stream>>>(x, xT);
    k_pack2<<<1152, 256, 0, stream>>>(Wx, Wh, Axp, Ahp);

    k_conv0<<<2048, 512, 0, stream>>>(xT, Axp, y, prt);
    k_bn_fin<<<256, 256, 0, stream>>>(prt, bx, gamma, beta, ss);

    unsigned short* hbuf[2] = {hA, hB};
    for (int t = 0; t < 16; ++t) {
        k_step<<<512, 256, 0, stream>>>(hbuf[t & 1], Ahp, y, ss, cs,
                                        hbuf[(t + 1) & 1], out, t, t == 0 ? 1 : 0);
    }
}